// Round 5
// baseline (1332.691 us; speedup 1.0000x reference)
//
#include <hip/hip_runtime.h>

typedef __attribute__((ext_vector_type(8))) short bf16x8;
typedef __attribute__((ext_vector_type(4))) float f32x4;

static constexpr int EN   = 524288;
static constexpr int NUE_ = 512;
static constexpr int NAP_ = 1024;
static constexpr int HID_ = 32;
static constexpr int OD_  = 60;
static constexpr int OC_  = 64;

__device__ __forceinline__ unsigned short f2bf(float x) {
  unsigned int u = __float_as_uint(x);
  return (unsigned short)((u + 0x7fffu + ((u >> 16) & 1u)) >> 16);  // RNE
}

// W rows [K0, K0+KREAL) of a [*, NREAL] fp32 matrix -> out [NPAD][KP] bf16 B^T
template<int NPAD, int NREAL, int KP, int KREAL, int K0>
__global__ __launch_bounds__(256)
void prep_w(const float* __restrict__ W, unsigned short* __restrict__ out) {
  int i = blockIdx.x * 256 + threadIdx.x;
  if (i >= NPAD * KP) return;
  int n = i / KP, k = i - n * KP;
  float v = (n < NREAL && k < KREAL) ? W[(size_t)(K0 + k) * NREAL + n] : 0.f;
  out[i] = f2bf(v);
}

template<int L, int KOUT>
__device__ __forceinline__ void accum_seg(const float* __restrict__ W, int krow0,
                                          const float* seg, float* acc) {
  #pragma unroll 1
  for (int k = 0; k < L; k += 4) {
    const float4 x = *reinterpret_cast<const float4*>(seg + k);
    const float xs[4] = {x.x, x.y, x.z, x.w};
    const float* __restrict__ wr = W + (size_t)(krow0 + k) * KOUT;
    #pragma unroll
    for (int j = 0; j < 4; ++j)
      #pragma unroll
      for (int o = 0; o < KOUT; ++o)
        acc[o] = fmaf(xs[j], wr[j * KOUT + o], acc[o]);
  }
}

// Node tables: Yje = xj @ Wje (no bias), Ym = xj @ Wm (+msg_b), Yie = xi @ Wie (+ew_b)
template<int LXJ, int LXI>
__global__ __launch_bounds__(256)
void tabs_kernel(const float* __restrict__ xj, int NJ,
                 const float* __restrict__ xi, int NI,
                 const float* __restrict__ Wje, const float* __restrict__ Wie,
                 const float* __restrict__ Wm,
                 const float* __restrict__ ew_b, const float* __restrict__ msg_b,
                 float* __restrict__ Yje, float* __restrict__ Yie,
                 float* __restrict__ Ym)
{
  int tid = blockIdx.x * 256 + threadIdx.x;
  if (tid < NJ) {
    const float* x = xj + (size_t)tid * LXJ;
    float a[OD_];
    #pragma unroll
    for (int o = 0; o < OD_; ++o) a[o] = 0.f;
    accum_seg<LXJ, OD_>(Wje, 0, x, a);
    for (int o = 0; o < OD_; ++o) Yje[(size_t)tid * OD_ + o] = a[o];
    float m[HID_];
    #pragma unroll
    for (int o = 0; o < HID_; ++o) m[o] = msg_b[o];
    accum_seg<LXJ, HID_>(Wm, 0, x, m);
    for (int o = 0; o < HID_; ++o) Ym[(size_t)tid * HID_ + o] = m[o];
  } else if (tid < NJ + NI) {
    int r = tid - NJ;
    const float* x = xi + (size_t)r * LXI;
    float a[OD_];
    #pragma unroll
    for (int o = 0; o < OD_; ++o) a[o] = ew_b[o];
    accum_seg<LXI, OD_>(Wie, 0, x, a);
    for (int o = 0; o < OD_; ++o) Yie[(size_t)r * OD_ + o] = a[o];
  }
}

// conv1/conv2 edge stage (LEA=4): 4 threads per edge; thread j owns ew cols
// [j*15,j*15+15) and msg cols [j*8,j*8+8). Tables hold the xj/xi parts.
template<bool WF32>
__global__ __launch_bounds__(256)
void edge12(const float* __restrict__ ea_in,
            const int* __restrict__ src_idx, const int* __restrict__ dst_idx,
            const float* __restrict__ Yje, const float* __restrict__ Yie,
            const float* __restrict__ Ym,
            const float* __restrict__ We,   // 4x60 (ea rows of ew_W)
            const float* __restrict__ Wm,   // 4x32
            float* __restrict__ agg,
            float* __restrict__ outF,            // [E][64] fp32 (WF32)
            unsigned short* __restrict__ outB)   // [E][64] bf16 (!WF32)
{
  const int gid = blockIdx.x * 256 + threadIdx.x;
  const int e = gid >> 2, j = gid & 3;
  const float4 ea = *reinterpret_cast<const float4*>(ea_in + (size_t)e * 4);
  const float eav[4] = {ea.x, ea.y, ea.z, ea.w};
  const int s = src_idx[e], d = dst_idx[e];
  const int c0 = j * 15;
  float acc[15];
  #pragma unroll
  for (int c = 0; c < 15; ++c)
    acc[c] = Yje[(size_t)s * OD_ + c0 + c] + Yie[(size_t)d * OD_ + c0 + c];
  #pragma unroll
  for (int k = 0; k < 4; ++k)
    #pragma unroll
    for (int c = 0; c < 15; ++c)
      acc[c] = fmaf(eav[k], We[k * OD_ + c0 + c], acc[c]);
  #pragma unroll
  for (int c = 0; c < 15; ++c) acc[c] = acc[c] >= 0.f ? acc[c] : 0.1f * acc[c];

  if constexpr (WF32) {
    float* orow = outF + (size_t)e * OC_;
    if (j == 0) *reinterpret_cast<float4*>(orow) = ea;
    #pragma unroll
    for (int c = 0; c < 15; ++c) orow[4 + c0 + c] = acc[c];
  } else {
    unsigned short* orow = outB + (size_t)e * OC_;
    if (j == 0) {
      orow[0] = f2bf(ea.x); orow[1] = f2bf(ea.y);
      orow[2] = f2bf(ea.z); orow[3] = f2bf(ea.w);
    }
    #pragma unroll
    for (int c = 0; c < 15; ++c) orow[4 + c0 + c] = f2bf(acc[c]);
  }
  // msg
  const int m0 = j * 8;
  float m[8];
  #pragma unroll
  for (int c = 0; c < 8; ++c) m[c] = Ym[(size_t)s * HID_ + m0 + c];
  #pragma unroll
  for (int k = 0; k < 4; ++k)
    #pragma unroll
    for (int c = 0; c < 8; ++c)
      m[c] = fmaf(eav[k], Wm[k * HID_ + m0 + c], m[c]);
  #pragma unroll
  for (int c = 0; c < 8; ++c) {
    float v = m[c] >= 0.f ? m[c] : 0.1f * m[c];
    atomicAdd(&agg[(size_t)d * HID_ + m0 + c], v);
  }
}

// conv3 edge stage: dense ea GEMM (K=64) + table adds. No LDS. 256 thr = 4 waves,
// wave owns 64 edges (4 MFMA A-tiles). FUSE: in-reg power head, writes [E,5].
template<bool FUSE>
__global__ __launch_bounds__(256)
void edge3(const float* eaF,                       // !FUSE: fp32 [E][64] (aliases ea_out!)
           const unsigned short* __restrict__ eaB, // FUSE: bf16 [E][64]
           const float* __restrict__ ea0_src,      // FUSE: original ea_down [E][4]
           const int* __restrict__ src_idx, const int* __restrict__ dst_idx,
           const unsigned short* __restrict__ Wet, const unsigned short* __restrict__ Wmt,
           const float* __restrict__ Yje, const float* __restrict__ Yie,
           const float* __restrict__ Ym,
           float* __restrict__ agg, float* ea_out,
           const float* __restrict__ pe1_W, const float* __restrict__ pe1_b,
           const float* __restrict__ pe2_W, const float* __restrict__ pe2_b,
           const float* __restrict__ ln_g,  const float* __restrict__ ln_b)
{
  const int t = threadIdx.x, l = t & 63, w = t >> 6;
  const int lr = l & 15, lkb = l >> 4;
  const int eW = blockIdx.x * 256 + w * 64;

  // B fragments in registers (weights ~hot in L2/L1)
  bf16x8 be[4][2], bm[2][2];
  #pragma unroll
  for (int nt = 0; nt < 4; ++nt)
    #pragma unroll
    for (int kk = 0; kk < 2; ++kk)
      be[nt][kk] = *reinterpret_cast<const bf16x8*>(Wet + (nt * 16 + lr) * 64 + kk * 32 + lkb * 8);
  #pragma unroll
  for (int nt = 0; nt < 2; ++nt)
    #pragma unroll
    for (int kk = 0; kk < 2; ++kk)
      bm[nt][kk] = *reinterpret_cast<const bf16x8*>(Wmt + (nt * 16 + lr) * 64 + kk * 32 + lkb * 8);

  #pragma unroll 1
  for (int tile = 0; tile < 4; ++tile) {
    const int e0 = eW + tile * 16;
    bf16x8 a[2];
    if constexpr (FUSE) {
      const unsigned short* ar = eaB + (size_t)(e0 + lr) * OC_ + lkb * 8;
      a[0] = *reinterpret_cast<const bf16x8*>(ar);
      a[1] = *reinterpret_cast<const bf16x8*>(ar + 32);
    } else {
      const float* ar = eaF + (size_t)(e0 + lr) * OC_ + lkb * 8;
      #pragma unroll
      for (int kk = 0; kk < 2; ++kk) {
        float4 f0 = *reinterpret_cast<const float4*>(ar + kk * 32);
        float4 f1 = *reinterpret_cast<const float4*>(ar + kk * 32 + 4);
        bf16x8 aa;
        aa[0] = (short)f2bf(f0.x); aa[1] = (short)f2bf(f0.y);
        aa[2] = (short)f2bf(f0.z); aa[3] = (short)f2bf(f0.w);
        aa[4] = (short)f2bf(f1.x); aa[5] = (short)f2bf(f1.y);
        aa[6] = (short)f2bf(f1.z); aa[7] = (short)f2bf(f1.w);
        a[kk] = aa;
      }
    }
    f32x4 accE[4] = {f32x4{0,0,0,0}, f32x4{0,0,0,0}, f32x4{0,0,0,0}, f32x4{0,0,0,0}};
    f32x4 accM[2] = {f32x4{0,0,0,0}, f32x4{0,0,0,0}};
    #pragma unroll
    for (int kk = 0; kk < 2; ++kk) {
      #pragma unroll
      for (int nt = 0; nt < 4; ++nt)
        accE[nt] = __builtin_amdgcn_mfma_f32_16x16x32_bf16(a[kk], be[nt][kk], accE[nt], 0, 0, 0);
      #pragma unroll
      for (int nt = 0; nt < 2; ++nt)
        accM[nt] = __builtin_amdgcn_mfma_f32_16x16x32_bf16(a[kk], bm[nt][kk], accM[nt], 0, 0, 0);
    }
    // epilogue: C/D row = lkb*4+r, col = nt*16+lr
    #pragma unroll
    for (int r = 0; r < 4; ++r) {
      const int e = e0 + lkb * 4 + r;
      const int s = src_idx[e], d = dst_idx[e];
      #pragma unroll
      for (int nt = 0; nt < 2; ++nt) {
        int col = nt * 16 + lr;
        float v = accM[nt][r] + Ym[(size_t)s * HID_ + col];
        v = v >= 0.f ? v : 0.1f * v;
        atomicAdd(&agg[(size_t)d * HID_ + col], v);
      }
      float val[4];
      #pragma unroll
      for (int nt = 0; nt < 4; ++nt) {
        int col = nt * 16 + lr;
        float v = (col < OD_)
            ? accE[nt][r] + Yje[(size_t)s * OD_ + col] + Yie[(size_t)d * OD_ + col]
            : 0.f;
        val[nt] = v >= 0.f ? v : 0.1f * v;
      }
      if constexpr (!FUSE) {
        #pragma unroll
        for (int nt = 0; nt < 4; ++nt) {
          int col = nt * 16 + lr;
          if (col < OD_) ea_out[(size_t)e * OC_ + 4 + col] = val[nt];
        }
      } else {
        float p4[4] = {0.f, 0.f, 0.f, 0.f};
        #pragma unroll
        for (int nt = 0; nt < 4; ++nt) {
          int col = nt * 16 + lr;
          if (col < OD_) {
            #pragma unroll
            for (int jj = 0; jj < 4; ++jj)
              p4[jj] = fmaf(val[nt], pe1_W[(4 + col) * 4 + jj], p4[jj]);
          }
        }
        #pragma unroll
        for (int mk = 1; mk < 16; mk <<= 1) {
          #pragma unroll
          for (int jj = 0; jj < 4; ++jj)
            p4[jj] += __shfl_xor(p4[jj], mk, 64);
        }
        const float4 ea0 = *reinterpret_cast<const float4*>(ea0_src + (size_t)e * 4);
        float v4[4];
        #pragma unroll
        for (int jj = 0; jj < 4; ++jj)
          v4[jj] = p4[jj] + pe1_b[jj]
                 + ea0.x * pe1_W[0 * 4 + jj] + ea0.y * pe1_W[1 * 4 + jj]
                 + ea0.z * pe1_W[2 * 4 + jj] + ea0.w * pe1_W[3 * 4 + jj];
        const float mu = 0.25f * (v4[0] + v4[1] + v4[2] + v4[3]);
        float var = 0.f;
        #pragma unroll
        for (int jj = 0; jj < 4; ++jj) { float dd = v4[jj] - mu; var = fmaf(dd, dd, var); }
        var *= 0.25f;
        const float rstd = rsqrtf(var + 1e-5f);
        float p = pe2_b[0];
        #pragma unroll
        for (int jj = 0; jj < 4; ++jj) {
          float h = (v4[jj] - mu) * rstd * ln_g[jj] + ln_b[jj];
          h = h >= 0.f ? h : 0.1f * h;
          p = fmaf(h, pe2_W[jj], p);
        }
        if (lr == 0) {
          float* orow = ea_out + (size_t)e * 5;
          orow[0] = ea0.x; orow[1] = ea0.y; orow[2] = ea0.z; orow[3] = ea0.w;
          orow[4] = p;
        }
      }
    }
  }
}

template<int LX, bool RES>
__global__ __launch_bounds__(256)
void node_kernel(const float* x_in, const float* __restrict__ agg,
                 const float* __restrict__ W, const float* __restrict__ b,
                 float* x_out, int N)
{
  const int n = blockIdx.x * blockDim.x + threadIdx.x;
  if (n >= N) return;
  const float* x = x_in + (size_t)n * LX;
  float acc[OD_];
  #pragma unroll
  for (int o = 0; o < OD_; ++o) acc[o] = b[o];
  accum_seg<LX,   OD_>(W, 0,  x, acc);
  accum_seg<HID_, OD_>(W, LX, agg + (size_t)n * HID_, acc);
  #pragma unroll
  for (int o = 0; o < OD_; ++o) acc[o] = acc[o] >= 0.f ? acc[o] : 0.1f * acc[o];
  if constexpr (RES)
    #pragma unroll
    for (int o = 0; o < OD_; ++o) acc[o] += x[4 + o];
  const float4 x0 = *reinterpret_cast<const float4*>(x);
  float* orow = x_out + (size_t)n * OC_;
  *reinterpret_cast<float4*>(orow) = x0;
  #pragma unroll
  for (int o = 0; o < OD_; o += 4)
    *reinterpret_cast<float4*>(orow + 4 + o) =
        make_float4(acc[o], acc[o + 1], acc[o + 2], acc[o + 3]);
}

extern "C" void kernel_launch(void* const* d_in, const int* in_sizes, int n_in,
                              void* d_out, int out_size, void* d_ws, size_t ws_size,
                              hipStream_t stream)
{
  const float* x_ue    = (const float*)d_in[0];
  const float* x_ap    = (const float*)d_in[1];
  const float* ea_up   = (const float*)d_in[2];
  const float* ea_down = (const float*)d_in[3];
  const int* up_src = (const int*)d_in[4];
  const int* up_dst = (const int*)d_in[5];
  const int* dn_src = (const int*)d_in[6];
  const int* dn_dst = (const int*)d_in[7];
  const float* c1_msg_W = (const float*)d_in[8];  const float* c1_msg_b = (const float*)d_in[9];
  const float* c1_upd_W = (const float*)d_in[10]; const float* c1_upd_b = (const float*)d_in[11];
  const float* c1_ew_W  = (const float*)d_in[12]; const float* c1_ew_b  = (const float*)d_in[13];
  const float* c2_msg_W = (const float*)d_in[14]; const float* c2_msg_b = (const float*)d_in[15];
  const float* c2_upd_W = (const float*)d_in[16]; const float* c2_upd_b = (const float*)d_in[17];
  const float* c2_ew_W  = (const float*)d_in[18]; const float* c2_ew_b  = (const float*)d_in[19];
  const float* c3u_msg_W= (const float*)d_in[20]; const float* c3u_msg_b= (const float*)d_in[21];
  const float* c3u_upd_W= (const float*)d_in[22]; const float* c3u_upd_b= (const float*)d_in[23];
  const float* c3u_ew_W = (const float*)d_in[24]; const float* c3u_ew_b = (const float*)d_in[25];
  const float* c3d_msg_W= (const float*)d_in[26]; const float* c3d_msg_b= (const float*)d_in[27];
  const float* c3d_upd_W= (const float*)d_in[28]; const float* c3d_upd_b= (const float*)d_in[29];
  const float* c3d_ew_W = (const float*)d_in[30]; const float* c3d_ew_b = (const float*)d_in[31];
  const float* pe1_W = (const float*)d_in[32]; const float* pe1_b = (const float*)d_in[33];
  const float* pe2_W = (const float*)d_in[34]; const float* pe2_b = (const float*)d_in[35];
  const float* ln_g  = (const float*)d_in[36]; const float* ln_b  = (const float*)d_in[37];

  float* out    = (float*)d_out;
  float* x_ue_o = out;
  float* x_ap_o = out + (size_t)NUE_ * OC_;
  float* ea_up_o = x_ap_o + (size_t)NAP_ * OC_;
  float* ea_dn_o = ea_up_o + (size_t)EN * OC_;

  float* ws = (float*)d_ws;
  float* agg1 = ws;                       // [1024][32]
  float* agg2 = agg1 + NAP_ * HID_;       // [512][32]
  float* agg3 = agg2 + NUE_ * HID_;       // [1024][32]
  float* agg4 = agg3 + NAP_ * HID_;       // [512][32]
  float* p = agg4 + NUE_ * HID_;
  float* Y1j = p;  p += NUE_ * OD_;  float* Y1i = p; p += NAP_ * OD_;  float* Y1m = p; p += NUE_ * HID_;
  float* Y2j = p;  p += NAP_ * OD_;  float* Y2i = p; p += NUE_ * OD_;  float* Y2m = p; p += NAP_ * HID_;
  float* Y3uj = p; p += NUE_ * OD_;  float* Y3ui = p; p += NAP_ * OD_; float* Y3um = p; p += NUE_ * HID_;
  float* Y3dj = p; p += NAP_ * OD_;  float* Y3di = p; p += NUE_ * OD_; float* Y3dm = p; p += NAP_ * HID_;
  unsigned short* us = (unsigned short*)p;
  unsigned short* ea_dn_bf = us;  us += (size_t)EN * OC_;   // 67 MB bf16 mirror
  unsigned short* we3u = us; us += 64 * 64;
  unsigned short* wm3u = us; us += 32 * 64;
  unsigned short* we3d = us; us += 64 * 64;
  unsigned short* wm3d = us; us += 32 * 64;

  hipMemsetAsync(ws, 0, sizeof(float) * (size_t)(NAP_ + NUE_) * 2 * HID_, stream);

  prep_w<64, 60, 64, 64, 64><<<16, 256, 0, stream>>>(c3u_ew_W,  we3u);
  prep_w<32, 32, 64, 64, 64><<<8,  256, 0, stream>>>(c3u_msg_W, wm3u);
  prep_w<64, 60, 64, 64, 64><<<16, 256, 0, stream>>>(c3d_ew_W,  we3d);
  prep_w<32, 32, 64, 64, 64><<<8,  256, 0, stream>>>(c3d_msg_W, wm3d);

  const dim3 blk(256);
  const dim3 eg12(EN * 4 / 256);   // 8192
  const dim3 eg3(EN / 256);        // 2048
  const dim3 tg(6);                // (512+1024)/256

  // conv1: UE --up--> AP
  tabs_kernel<4, 4><<<tg, blk, 0, stream>>>(
      x_ue, NUE_, x_ap, NAP_, c1_ew_W, c1_ew_W + 8 * OD_, c1_msg_W,
      c1_ew_b, c1_msg_b, Y1j, Y1i, Y1m);
  edge12<true><<<eg12, blk, 0, stream>>>(
      ea_up, up_src, up_dst, Y1j, Y1i, Y1m,
      c1_ew_W + 4 * OD_, c1_msg_W + 4 * HID_, agg1, ea_up_o, nullptr);
  node_kernel<4, false><<<dim3(NAP_ / 256), blk, 0, stream>>>(
      x_ap, agg1, c1_upd_W, c1_upd_b, x_ap_o, NAP_);

  // conv2: AP --down--> UE (bf16 mirror only)
  tabs_kernel<64, 4><<<tg, blk, 0, stream>>>(
      x_ap_o, NAP_, x_ue, NUE_, c2_ew_W, c2_ew_W + 68 * OD_, c2_msg_W,
      c2_ew_b, c2_msg_b, Y2j, Y2i, Y2m);
  edge12<false><<<eg12, blk, 0, stream>>>(
      ea_down, dn_src, dn_dst, Y2j, Y2i, Y2m,
      c2_ew_W + 64 * OD_, c2_msg_W + 64 * HID_, agg2, nullptr, ea_dn_bf);
  node_kernel<4, false><<<dim3(NUE_ / 256), blk, 0, stream>>>(
      x_ue, agg2, c2_upd_W, c2_upd_b, x_ue_o, NUE_);

  // conv3u: UE --up--> AP; ea_up_o updated in place (cols 4..63)
  tabs_kernel<64, 64><<<tg, blk, 0, stream>>>(
      x_ue_o, NUE_, x_ap_o, NAP_, c3u_ew_W, c3u_ew_W + 128 * OD_, c3u_msg_W,
      c3u_ew_b, c3u_msg_b, Y3uj, Y3ui, Y3um);
  edge3<false><<<eg3, blk, 0, stream>>>(
      ea_up_o, nullptr, nullptr, up_src, up_dst, we3u, wm3u,
      Y3uj, Y3ui, Y3um, agg3, ea_up_o,
      nullptr, nullptr, nullptr, nullptr, nullptr, nullptr);
  node_kernel<64, true><<<dim3(NAP_ / 256), blk, 0, stream>>>(
      x_ap_o, agg3, c3u_upd_W, c3u_upd_b, x_ap_o, NAP_);

  // conv3d: AP --down--> UE + fused power head -> [E,5]
  tabs_kernel<64, 64><<<tg, blk, 0, stream>>>(
      x_ap_o, NAP_, x_ue_o, NUE_, c3d_ew_W, c3d_ew_W + 128 * OD_, c3d_msg_W,
      c3d_ew_b, c3d_msg_b, Y3dj, Y3di, Y3dm);
  edge3<true><<<eg3, blk, 0, stream>>>(
      nullptr, ea_dn_bf, ea_down, dn_src, dn_dst, we3d, wm3d,
      Y3dj, Y3di, Y3dm, agg4, ea_dn_o,
      pe1_W, pe1_b, pe2_W, pe2_b, ln_g, ln_b);
  node_kernel<64, true><<<dim3(NUE_ / 256), blk, 0, stream>>>(
      x_ue_o, agg4, c3d_upd_W, c3d_upd_b, x_ue_o, NUE_);
}

// Round 6
// 673.883 us; speedup vs baseline: 1.9776x; 1.9776x over previous
//
#include <hip/hip_runtime.h>

typedef __attribute__((ext_vector_type(8))) short bf16x8;
typedef __attribute__((ext_vector_type(4))) float f32x4;

static constexpr int EN   = 524288;
static constexpr int NUE_ = 512;
static constexpr int NAP_ = 1024;
static constexpr int HID_ = 32;
static constexpr int OD_  = 60;
static constexpr int OC_  = 64;

__device__ __forceinline__ unsigned short f2bf(float x) {
  unsigned int u = __float_as_uint(x);
  return (unsigned short)((u + 0x7fffu + ((u >> 16) & 1u)) >> 16);  // RNE
}

// W rows [K0, K0+KREAL) of a [*, NREAL] fp32 matrix -> out [NPAD][KP] bf16 B^T
template<int NPAD, int NREAL, int KP, int KREAL, int K0>
__global__ __launch_bounds__(256)
void prep_w(const float* __restrict__ W, unsigned short* __restrict__ out) {
  int i = blockIdx.x * 256 + threadIdx.x;
  if (i >= NPAD * KP) return;
  int n = i / KP, k = i - n * KP;
  float v = (n < NREAL && k < KREAL) ? W[(size_t)(K0 + k) * NREAL + n] : 0.f;
  out[i] = f2bf(v);
}

template<int L, int KOUT>
__device__ __forceinline__ void accum_seg(const float* __restrict__ W, int krow0,
                                          const float* seg, float* acc) {
  #pragma unroll 1
  for (int k = 0; k < L; k += 4) {
    const float4 x = *reinterpret_cast<const float4*>(seg + k);
    const float xs[4] = {x.x, x.y, x.z, x.w};
    const float* __restrict__ wr = W + (size_t)(krow0 + k) * KOUT;
    #pragma unroll
    for (int j = 0; j < 4; ++j)
      #pragma unroll
      for (int o = 0; o < KOUT; ++o)
        acc[o] = fmaf(xs[j], wr[j * KOUT + o], acc[o]);
  }
}

// Node tables: Yje = xj @ Wje (no bias), Ym = xj @ Wm (+msg_b), Yie = xi @ Wie (+ew_b)
template<int LXJ, int LXI>
__global__ __launch_bounds__(256)
void tabs_kernel(const float* __restrict__ xj, int NJ,
                 const float* __restrict__ xi, int NI,
                 const float* __restrict__ Wje, const float* __restrict__ Wie,
                 const float* __restrict__ Wm,
                 const float* __restrict__ ew_b, const float* __restrict__ msg_b,
                 float* __restrict__ Yje, float* __restrict__ Yie,
                 float* __restrict__ Ym)
{
  int tid = blockIdx.x * 256 + threadIdx.x;
  if (tid < NJ) {
    const float* x = xj + (size_t)tid * LXJ;
    float a[OD_];
    #pragma unroll
    for (int o = 0; o < OD_; ++o) a[o] = 0.f;
    accum_seg<LXJ, OD_>(Wje, 0, x, a);
    for (int o = 0; o < OD_; ++o) Yje[(size_t)tid * OD_ + o] = a[o];
    float m[HID_];
    #pragma unroll
    for (int o = 0; o < HID_; ++o) m[o] = msg_b[o];
    accum_seg<LXJ, HID_>(Wm, 0, x, m);
    for (int o = 0; o < HID_; ++o) Ym[(size_t)tid * HID_ + o] = m[o];
  } else if (tid < NJ + NI) {
    int r = tid - NJ;
    const float* x = xi + (size_t)r * LXI;
    float a[OD_];
    #pragma unroll
    for (int o = 0; o < OD_; ++o) a[o] = ew_b[o];
    accum_seg<LXI, OD_>(Wie, 0, x, a);
    for (int o = 0; o < OD_; ++o) Yie[(size_t)r * OD_ + o] = a[o];
  }
}

// conv1/conv2 edge stage (LEA=4): block = 64 edges, 4 threads/edge compute.
// Results staged in LDS, then: coalesced bf16 row writes + wave-coalesced
// atomics (one instruction covers whole 128B agg rows).
__global__ __launch_bounds__(256)
void edge12(const float* __restrict__ ea_in,
            const int* __restrict__ src_idx, const int* __restrict__ dst_idx,
            const float* __restrict__ Yje, const float* __restrict__ Yie,
            const float* __restrict__ Ym,
            const float* __restrict__ We,   // 4x60 (ea rows of ew_W)
            const float* __restrict__ Wm,   // 4x32
            float* __restrict__ agg,
            unsigned short* __restrict__ outB)   // [E][64] bf16 mirror
{
  __shared__ unsigned short Eb[64 * 72];  // row stride 144B = 9*16B
  __shared__ float Mb[64 * 33];           // pad 33: conflict-free both phases
  const int t = threadIdx.x;
  const int eBase = blockIdx.x * 64;
  const int r = t >> 2, j = t & 3;
  const int e = eBase + r;
  const float4 ea = *reinterpret_cast<const float4*>(ea_in + (size_t)e * 4);
  const float eav[4] = {ea.x, ea.y, ea.z, ea.w};
  const int s = src_idx[e], d = dst_idx[e];

  // ew cols [j*15, j*15+15)
  const int c0 = j * 15;
  float acc[15];
  #pragma unroll
  for (int c = 0; c < 15; ++c)
    acc[c] = Yje[(size_t)s * OD_ + c0 + c] + Yie[(size_t)d * OD_ + c0 + c];
  #pragma unroll
  for (int k = 0; k < 4; ++k)
    #pragma unroll
    for (int c = 0; c < 15; ++c)
      acc[c] = fmaf(eav[k], We[k * OD_ + c0 + c], acc[c]);
  #pragma unroll
  for (int c = 0; c < 15; ++c) {
    float v = acc[c] >= 0.f ? acc[c] : 0.1f * acc[c];
    Eb[r * 72 + 4 + c0 + c] = f2bf(v);
  }
  if (j == 0) {
    Eb[r * 72 + 0] = f2bf(ea.x); Eb[r * 72 + 1] = f2bf(ea.y);
    Eb[r * 72 + 2] = f2bf(ea.z); Eb[r * 72 + 3] = f2bf(ea.w);
  }
  // msg cols [j*8, j*8+8)
  const int m0 = j * 8;
  float m[8];
  #pragma unroll
  for (int c = 0; c < 8; ++c) m[c] = Ym[(size_t)s * HID_ + m0 + c];
  #pragma unroll
  for (int k = 0; k < 4; ++k)
    #pragma unroll
    for (int c = 0; c < 8; ++c)
      m[c] = fmaf(eav[k], Wm[k * HID_ + m0 + c], m[c]);
  #pragma unroll
  for (int c = 0; c < 8; ++c)
    Mb[r * 33 + m0 + c] = m[c] >= 0.f ? m[c] : 0.1f * m[c];
  __syncthreads();

  // coalesced bf16 row writes: 64 rows x 128B
  #pragma unroll
  for (int i = 0; i < 2; ++i) {
    int idx = t + i * 256;
    int row = idx >> 3, ch = idx & 7;
    *reinterpret_cast<uint4*>(outB + (size_t)(eBase + row) * OC_ + ch * 8) =
        *reinterpret_cast<const uint4*>(&Eb[row * 72 + ch * 8]);
  }
  // wave-coalesced atomics: instruction i covers rows {i*8+(t>>5)} cols t&31
  #pragma unroll
  for (int i = 0; i < 8; ++i) {
    int rl = i * 8 + (t >> 5), col = t & 31;
    int dd = dst_idx[eBase + rl];
    atomicAdd(&agg[(size_t)dd * HID_ + col], Mb[rl * 33 + col]);
  }
}

// conv3 edge stage: dense bf16 ea GEMM (K=64) + table adds. No LDS.
// 256 thr = 4 waves, wave owns 64 edges. FUSE: in-reg power head -> [E,5].
template<bool FUSE>
__global__ __launch_bounds__(256)
void edge3(const unsigned short* __restrict__ eaB, // bf16 [E][64]
           const float* __restrict__ ea0_src,      // original ea [E][4] (cols 0..3)
           const int* __restrict__ src_idx, const int* __restrict__ dst_idx,
           const unsigned short* __restrict__ Wet, const unsigned short* __restrict__ Wmt,
           const float* __restrict__ Yje, const float* __restrict__ Yie,
           const float* __restrict__ Ym,
           float* __restrict__ agg, float* __restrict__ ea_out,
           const float* __restrict__ pe1_W, const float* __restrict__ pe1_b,
           const float* __restrict__ pe2_W, const float* __restrict__ pe2_b,
           const float* __restrict__ ln_g,  const float* __restrict__ ln_b)
{
  const int t = threadIdx.x, l = t & 63, w = t >> 6;
  const int lr = l & 15, lkb = l >> 4;
  const int eW = blockIdx.x * 256 + w * 64;

  // B fragments in registers (weights hot in L1/L2)
  bf16x8 be[4][2], bm[2][2];
  #pragma unroll
  for (int nt = 0; nt < 4; ++nt)
    #pragma unroll
    for (int kk = 0; kk < 2; ++kk)
      be[nt][kk] = *reinterpret_cast<const bf16x8*>(Wet + (nt * 16 + lr) * 64 + kk * 32 + lkb * 8);
  #pragma unroll
  for (int nt = 0; nt < 2; ++nt)
    #pragma unroll
    for (int kk = 0; kk < 2; ++kk)
      bm[nt][kk] = *reinterpret_cast<const bf16x8*>(Wmt + (nt * 16 + lr) * 64 + kk * 32 + lkb * 8);

  #pragma unroll 1
  for (int tile = 0; tile < 4; ++tile) {
    const int e0 = eW + tile * 16;
    const unsigned short* ar = eaB + (size_t)(e0 + lr) * OC_ + lkb * 8;
    bf16x8 a[2];
    a[0] = *reinterpret_cast<const bf16x8*>(ar);
    a[1] = *reinterpret_cast<const bf16x8*>(ar + 32);

    f32x4 accE[4] = {f32x4{0,0,0,0}, f32x4{0,0,0,0}, f32x4{0,0,0,0}, f32x4{0,0,0,0}};
    f32x4 accM[2] = {f32x4{0,0,0,0}, f32x4{0,0,0,0}};
    #pragma unroll
    for (int kk = 0; kk < 2; ++kk) {
      #pragma unroll
      for (int nt = 0; nt < 4; ++nt)
        accE[nt] = __builtin_amdgcn_mfma_f32_16x16x32_bf16(a[kk], be[nt][kk], accE[nt], 0, 0, 0);
      #pragma unroll
      for (int nt = 0; nt < 2; ++nt)
        accM[nt] = __builtin_amdgcn_mfma_f32_16x16x32_bf16(a[kk], bm[nt][kk], accM[nt], 0, 0, 0);
    }
    // epilogue: C/D row = lkb*4+r, col = nt*16+lr
    #pragma unroll
    for (int r = 0; r < 4; ++r) {
      const int e = e0 + lkb * 4 + r;
      const int s = src_idx[e], d = dst_idx[e];
      #pragma unroll
      for (int nt = 0; nt < 2; ++nt) {
        int col = nt * 16 + lr;
        float v = accM[nt][r] + Ym[(size_t)s * HID_ + col];
        v = v >= 0.f ? v : 0.1f * v;
        atomicAdd(&agg[(size_t)d * HID_ + col], v);
      }
      float val[4];
      #pragma unroll
      for (int nt = 0; nt < 4; ++nt) {
        int col = nt * 16 + lr;
        float v = (col < OD_)
            ? accE[nt][r] + Yje[(size_t)s * OD_ + col] + Yie[(size_t)d * OD_ + col]
            : 0.f;
        val[nt] = v >= 0.f ? v : 0.1f * v;
      }
      if constexpr (!FUSE) {
        #pragma unroll
        for (int nt = 0; nt < 4; ++nt) {
          int col = nt * 16 + lr;
          if (col < OD_) ea_out[(size_t)e * OC_ + 4 + col] = val[nt];
        }
        if (lr == 0) {
          float4 ea0 = *reinterpret_cast<const float4*>(ea0_src + (size_t)e * 4);
          *reinterpret_cast<float4*>(ea_out + (size_t)e * OC_) = ea0;
        }
      } else {
        float p4[4] = {0.f, 0.f, 0.f, 0.f};
        #pragma unroll
        for (int nt = 0; nt < 4; ++nt) {
          int col = nt * 16 + lr;
          if (col < OD_) {
            #pragma unroll
            for (int jj = 0; jj < 4; ++jj)
              p4[jj] = fmaf(val[nt], pe1_W[(4 + col) * 4 + jj], p4[jj]);
          }
        }
        #pragma unroll
        for (int mk = 1; mk < 16; mk <<= 1) {
          #pragma unroll
          for (int jj = 0; jj < 4; ++jj)
            p4[jj] += __shfl_xor(p4[jj], mk, 64);
        }
        const float4 ea0 = *reinterpret_cast<const float4*>(ea0_src + (size_t)e * 4);
        float v4[4];
        #pragma unroll
        for (int jj = 0; jj < 4; ++jj)
          v4[jj] = p4[jj] + pe1_b[jj]
                 + ea0.x * pe1_W[0 * 4 + jj] + ea0.y * pe1_W[1 * 4 + jj]
                 + ea0.z * pe1_W[2 * 4 + jj] + ea0.w * pe1_W[3 * 4 + jj];
        const float mu = 0.25f * (v4[0] + v4[1] + v4[2] + v4[3]);
        float var = 0.f;
        #pragma unroll
        for (int jj = 0; jj < 4; ++jj) { float dd = v4[jj] - mu; var = fmaf(dd, dd, var); }
        var *= 0.25f;
        const float rstd = rsqrtf(var + 1e-5f);
        float p = pe2_b[0];
        #pragma unroll
        for (int jj = 0; jj < 4; ++jj) {
          float h = (v4[jj] - mu) * rstd * ln_g[jj] + ln_b[jj];
          h = h >= 0.f ? h : 0.1f * h;
          p = fmaf(h, pe2_W[jj], p);
        }
        if (lr == 0) {
          float* orow = ea_out + (size_t)e * 5;
          orow[0] = ea0.x; orow[1] = ea0.y; orow[2] = ea0.z; orow[3] = ea0.w;
          orow[4] = p;
        }
      }
    }
  }
}

template<int LX, bool RES>
__global__ __launch_bounds__(256)
void node_kernel(const float* x_in, const float* __restrict__ agg,
                 const float* __restrict__ W, const float* __restrict__ b,
                 float* x_out, int N)
{
  const int n = blockIdx.x * blockDim.x + threadIdx.x;
  if (n >= N) return;
  const float* x = x_in + (size_t)n * LX;
  float acc[OD_];
  #pragma unroll
  for (int o = 0; o < OD_; ++o) acc[o] = b[o];
  accum_seg<LX,   OD_>(W, 0,  x, acc);
  accum_seg<HID_, OD_>(W, LX, agg + (size_t)n * HID_, acc);
  #pragma unroll
  for (int o = 0; o < OD_; ++o) acc[o] = acc[o] >= 0.f ? acc[o] : 0.1f * acc[o];
  if constexpr (RES)
    #pragma unroll
    for (int o = 0; o < OD_; ++o) acc[o] += x[4 + o];
  const float4 x0 = *reinterpret_cast<const float4*>(x);
  float* orow = x_out + (size_t)n * OC_;
  *reinterpret_cast<float4*>(orow) = x0;
  #pragma unroll
  for (int o = 0; o < OD_; o += 4)
    *reinterpret_cast<float4*>(orow + 4 + o) =
        make_float4(acc[o], acc[o + 1], acc[o + 2], acc[o + 3]);
}

extern "C" void kernel_launch(void* const* d_in, const int* in_sizes, int n_in,
                              void* d_out, int out_size, void* d_ws, size_t ws_size,
                              hipStream_t stream)
{
  const float* x_ue    = (const float*)d_in[0];
  const float* x_ap    = (const float*)d_in[1];
  const float* ea_up   = (const float*)d_in[2];
  const float* ea_down = (const float*)d_in[3];
  const int* up_src = (const int*)d_in[4];
  const int* up_dst = (const int*)d_in[5];
  const int* dn_src = (const int*)d_in[6];
  const int* dn_dst = (const int*)d_in[7];
  const float* c1_msg_W = (const float*)d_in[8];  const float* c1_msg_b = (const float*)d_in[9];
  const float* c1_upd_W = (const float*)d_in[10]; const float* c1_upd_b = (const float*)d_in[11];
  const float* c1_ew_W  = (const float*)d_in[12]; const float* c1_ew_b  = (const float*)d_in[13];
  const float* c2_msg_W = (const float*)d_in[14]; const float* c2_msg_b = (const float*)d_in[15];
  const float* c2_upd_W = (const float*)d_in[16]; const float* c2_upd_b = (const float*)d_in[17];
  const float* c2_ew_W  = (const float*)d_in[18]; const float* c2_ew_b  = (const float*)d_in[19];
  const float* c3u_msg_W= (const float*)d_in[20]; const float* c3u_msg_b= (const float*)d_in[21];
  const float* c3u_upd_W= (const float*)d_in[22]; const float* c3u_upd_b= (const float*)d_in[23];
  const float* c3u_ew_W = (const float*)d_in[24]; const float* c3u_ew_b = (const float*)d_in[25];
  const float* c3d_msg_W= (const float*)d_in[26]; const float* c3d_msg_b= (const float*)d_in[27];
  const float* c3d_upd_W= (const float*)d_in[28]; const float* c3d_upd_b= (const float*)d_in[29];
  const float* c3d_ew_W = (const float*)d_in[30]; const float* c3d_ew_b = (const float*)d_in[31];
  const float* pe1_W = (const float*)d_in[32]; const float* pe1_b = (const float*)d_in[33];
  const float* pe2_W = (const float*)d_in[34]; const float* pe2_b = (const float*)d_in[35];
  const float* ln_g  = (const float*)d_in[36]; const float* ln_b  = (const float*)d_in[37];

  float* out    = (float*)d_out;
  float* x_ue_o = out;
  float* x_ap_o = out + (size_t)NUE_ * OC_;
  float* ea_up_o = x_ap_o + (size_t)NAP_ * OC_;
  float* ea_dn_o = ea_up_o + (size_t)EN * OC_;

  float* ws = (float*)d_ws;
  float* agg1 = ws;                       // [1024][32]
  float* agg2 = agg1 + NAP_ * HID_;       // [512][32]
  float* agg3 = agg2 + NUE_ * HID_;       // [1024][32]
  float* agg4 = agg3 + NAP_ * HID_;       // [512][32]
  float* p = agg4 + NUE_ * HID_;
  float* Y1j = p;  p += NUE_ * OD_;  float* Y1i = p; p += NAP_ * OD_;  float* Y1m = p; p += NUE_ * HID_;
  float* Y2j = p;  p += NAP_ * OD_;  float* Y2i = p; p += NUE_ * OD_;  float* Y2m = p; p += NAP_ * HID_;
  float* Y3uj = p; p += NUE_ * OD_;  float* Y3ui = p; p += NAP_ * OD_; float* Y3um = p; p += NUE_ * HID_;
  float* Y3dj = p; p += NAP_ * OD_;  float* Y3di = p; p += NUE_ * OD_; float* Y3dm = p; p += NAP_ * HID_;
  unsigned short* us = (unsigned short*)p;
  unsigned short* ea_up_bf = us;  us += (size_t)EN * OC_;   // 67 MB bf16 mirror
  unsigned short* ea_dn_bf = us;  us += (size_t)EN * OC_;   // 67 MB bf16 mirror
  unsigned short* we3u = us; us += 64 * 64;
  unsigned short* wm3u = us; us += 32 * 64;
  unsigned short* we3d = us; us += 64 * 64;
  unsigned short* wm3d = us; us += 32 * 64;

  hipMemsetAsync(ws, 0, sizeof(float) * (size_t)(NAP_ + NUE_) * 2 * HID_, stream);

  prep_w<64, 60, 64, 64, 64><<<16, 256, 0, stream>>>(c3u_ew_W,  we3u);
  prep_w<32, 32, 64, 64, 64><<<8,  256, 0, stream>>>(c3u_msg_W, wm3u);
  prep_w<64, 60, 64, 64, 64><<<16, 256, 0, stream>>>(c3d_ew_W,  we3d);
  prep_w<32, 32, 64, 64, 64><<<8,  256, 0, stream>>>(c3d_msg_W, wm3d);

  const dim3 blk(256);
  const dim3 eg12(EN / 64);        // 8192
  const dim3 eg3(EN / 256);        // 2048
  const dim3 tg(6);                // (512+1024)/256

  // conv1: UE --up--> AP  (bf16 mirror only; final ea_up written by conv3u)
  tabs_kernel<4, 4><<<tg, blk, 0, stream>>>(
      x_ue, NUE_, x_ap, NAP_, c1_ew_W, c1_ew_W + 8 * OD_, c1_msg_W,
      c1_ew_b, c1_msg_b, Y1j, Y1i, Y1m);
  edge12<<<eg12, blk, 0, stream>>>(
      ea_up, up_src, up_dst, Y1j, Y1i, Y1m,
      c1_ew_W + 4 * OD_, c1_msg_W + 4 * HID_, agg1, ea_up_bf);
  node_kernel<4, false><<<dim3(NAP_ / 256), blk, 0, stream>>>(
      x_ap, agg1, c1_upd_W, c1_upd_b, x_ap_o, NAP_);

  // conv2: AP --down--> UE (bf16 mirror only)
  tabs_kernel<64, 4><<<tg, blk, 0, stream>>>(
      x_ap_o, NAP_, x_ue, NUE_, c2_ew_W, c2_ew_W + 68 * OD_, c2_msg_W,
      c2_ew_b, c2_msg_b, Y2j, Y2i, Y2m);
  edge12<<<eg12, blk, 0, stream>>>(
      ea_down, dn_src, dn_dst, Y2j, Y2i, Y2m,
      c2_ew_W + 64 * OD_, c2_msg_W + 64 * HID_, agg2, ea_dn_bf);
  node_kernel<4, false><<<dim3(NUE_ / 256), blk, 0, stream>>>(
      x_ue, agg2, c2_upd_W, c2_upd_b, x_ue_o, NUE_);

  // conv3u: UE --up--> AP; writes full ea_up_o rows (cols 0..3 from original)
  tabs_kernel<64, 64><<<tg, blk, 0, stream>>>(
      x_ue_o, NUE_, x_ap_o, NAP_, c3u_ew_W, c3u_ew_W + 128 * OD_, c3u_msg_W,
      c3u_ew_b, c3u_msg_b, Y3uj, Y3ui, Y3um);
  edge3<false><<<eg3, blk, 0, stream>>>(
      ea_up_bf, ea_up, up_src, up_dst, we3u, wm3u,
      Y3uj, Y3ui, Y3um, agg3, ea_up_o,
      nullptr, nullptr, nullptr, nullptr, nullptr, nullptr);
  node_kernel<64, true><<<dim3(NAP_ / 256), blk, 0, stream>>>(
      x_ap_o, agg3, c3u_upd_W, c3u_upd_b, x_ap_o, NAP_);

  // conv3d: AP --down--> UE + fused power head -> [E,5]
  tabs_kernel<64, 64><<<tg, blk, 0, stream>>>(
      x_ap_o, NAP_, x_ue_o, NUE_, c3d_ew_W, c3d_ew_W + 128 * OD_, c3d_msg_W,
      c3d_ew_b, c3d_msg_b, Y3dj, Y3di, Y3dm);
  edge3<true><<<eg3, blk, 0, stream>>>(
      ea_dn_bf, ea_down, dn_src, dn_dst, we3d, wm3d,
      Y3dj, Y3di, Y3dm, agg4, ea_dn_o,
      pe1_W, pe1_b, pe2_W, pe2_b, ln_g, ln_b);
  node_kernel<64, true><<<dim3(NUE_ / 256), blk, 0, stream>>>(
      x_ue_o, agg4, c3d_upd_W, c3d_upd_b, x_ue_o, NUE_);
}